// Round 1
// 605.165 us; speedup vs baseline: 1.1173x; 1.1173x over previous
//
#include <hip/hip_runtime.h>

typedef __attribute__((ext_vector_type(8))) short short8;
typedef __attribute__((ext_vector_type(4))) float floatx4;

#define GLOBAL_AS __attribute__((address_space(1)))
#define LDS_AS __attribute__((address_space(3)))

__device__ __forceinline__ void gload_lds16(const void* g, void* l) {
  __builtin_amdgcn_global_load_lds((const GLOBAL_AS unsigned int*)g,
                                   (LDS_AS unsigned int*)l, 16, 0, 0);
}

__device__ __forceinline__ unsigned short rnbf(float f) {
  unsigned int v = __builtin_bit_cast(unsigned int, f);
  return (unsigned short)((v + 0x7fff + ((v >> 16) & 1)) >> 16);
}
__device__ __forceinline__ float bflo(unsigned int u) {
  return __builtin_bit_cast(float, u << 16);
}
__device__ __forceinline__ float bfhi(unsigned int u) {
  return __builtin_bit_cast(float, u & 0xffff0000u);
}

// ================= bf16 MFMA GEMM: C[M,N] = A[M,K] @ Bt[N,K]^T ==============
// 128x128 tile, BK=64, 256 thr = 4 waves in 2x2, each wave 64x64 (4x4 MFMA).
// Staging: global_load_lds width=16 with XOR chunk swizzle (unchanged).
#define TM 128
#define TN 128
#define BKE 64

__global__ __launch_bounds__(256) void gemm_bf16(
    const unsigned short* __restrict__ A,   // [M,K] bf16
    const unsigned short* __restrict__ Bt,  // [N,K] bf16 (= B^T)
    unsigned short* __restrict__ C,         // [M,N] bf16
    int M, int N, int K) {
  __shared__ __align__(16) unsigned short As[TM * BKE];
  __shared__ __align__(16) unsigned short Bs[TN * BKE];

  const int tid  = threadIdx.x;
  const int wave = tid >> 6;
  const int lane = tid & 63;
  const int wm = wave >> 1, wn = wave & 1;
  const int l15 = lane & 15, quad = lane >> 4;

  const int bm = blockIdx.y * TM;
  const int bn = blockIdx.x * TN;

  floatx4 acc[4][4];
#pragma unroll
  for (int i = 0; i < 4; ++i)
#pragma unroll
    for (int j = 0; j < 4; ++j) acc[i][j] = (floatx4){0.f, 0.f, 0.f, 0.f};

  const unsigned short* aptr[4];
  const unsigned short* bptr[4];
  int ldsoff[4];
#pragma unroll
  for (int j = 0; j < 4; ++j) {
    int ci = (wave * 4 + j) * 64 + lane;   // chunk index in tile
    int r  = ci >> 3;                      // local row 0..127
    int cs = (ci & 7) ^ (r & 7);           // swizzled source chunk
    int arow = bm + r; if (arow >= M) arow = M - 1;  // clamp; stores guarded
    aptr[j] = A  + (size_t)arow * K + cs * 8;
    bptr[j] = Bt + (size_t)(bn + r) * K + cs * 8;    // N % 128 == 0
    ldsoff[j] = (wave * 4 + j) * 64 * 8;   // ushort offset of chunk base
  }

  for (int k0 = 0; k0 < K; k0 += BKE) {
#pragma unroll
    for (int j = 0; j < 4; ++j) {
      gload_lds16(aptr[j] + k0, &As[ldsoff[j]]);
      gload_lds16(bptr[j] + k0, &Bs[ldsoff[j]]);
    }
    __syncthreads();   // drains vmcnt (global_load_lds) + lgkm
#pragma unroll
    for (int s = 0; s < 2; ++s) {
      short8 af[4], bf[4];
#pragma unroll
      for (int mt = 0; mt < 4; ++mt) {
        int mrow = wm * 64 + mt * 16 + l15;
        int sw = (s * 4 + quad) ^ (mrow & 7);
        af[mt] = *(const short8*)&As[(mrow * 8 + sw) * 8];
      }
#pragma unroll
      for (int nt = 0; nt < 4; ++nt) {
        int nrow = wn * 64 + nt * 16 + l15;
        int sw = (s * 4 + quad) ^ (nrow & 7);
        bf[nt] = *(const short8*)&Bs[(nrow * 8 + sw) * 8];
      }
#pragma unroll
      for (int mt = 0; mt < 4; ++mt)
#pragma unroll
        for (int nt = 0; nt < 4; ++nt)
          acc[mt][nt] = __builtin_amdgcn_mfma_f32_16x16x32_bf16(
              af[mt], bf[nt], acc[mt][nt], 0, 0, 0);
    }
    __syncthreads();
  }

  // epilogue: C/D layout col=lane&15, row=quad*4+i  (m89/m91-verified)
#pragma unroll
  for (int mt = 0; mt < 4; ++mt) {
#pragma unroll
    for (int nt = 0; nt < 4; ++nt) {
      const int col = bn + wn * 64 + nt * 16 + l15;
#pragma unroll
      for (int i = 0; i < 4; ++i) {
        const int row = bm + wm * 64 + mt * 16 + quad * 4 + i;
        if (row < M) C[(size_t)row * N + col] = rnbf(acc[mt][nt][i]);
      }
    }
  }
}

// ----------------------------- casts ---------------------------------------
__global__ __launch_bounds__(256) void cast_f32_to_bf16(
    const float* __restrict__ in, unsigned short* __restrict__ out,
    long long n4) {
  long long i = (long long)blockIdx.x * 256 + threadIdx.x;
  if (i >= n4) return;
  float4 v = ((const float4*)in)[i];
  ushort4 o;
  o.x = rnbf(v.x); o.y = rnbf(v.y); o.z = rnbf(v.z); o.w = rnbf(v.w);
  ((ushort4*)out)[i] = o;
}

// in [K][N] f32 -> out [N][K] bf16; K,N multiples of 32
__global__ __launch_bounds__(256) void transpose_cast_bf16(
    const float* __restrict__ in, unsigned short* __restrict__ out,
    int K, int N) {
  __shared__ float t[32][33];
  const int bx = blockIdx.x * 32;  // n
  const int by = blockIdx.y * 32;  // k
  const int tx = threadIdx.x & 31, ty = threadIdx.x >> 5;
#pragma unroll
  for (int j = 0; j < 4; ++j)
    t[ty + j * 8][tx] = in[(size_t)(by + ty + j * 8) * N + bx + tx];
  __syncthreads();
#pragma unroll
  for (int j = 0; j < 4; ++j)
    out[(size_t)(bx + ty + j * 8) * K + by + tx] = rnbf(t[tx][ty + j * 8]);
}

// ----------------------- CSR build -----------------------------------------
__global__ __launch_bounds__(256) void hist_dst(
    const int* __restrict__ dst, int* __restrict__ cnt, int E) {
  int e = blockIdx.x * blockDim.x + threadIdx.x;
  if (e < E) atomicAdd(&cnt[dst[e]], 1);
}

// single-block scan, wave-shfl based: 3 barriers/chunk instead of 20.
__global__ __launch_bounds__(1024) void scan_csr(
    int* __restrict__ cursor, int* __restrict__ rowptr, int n) {
  __shared__ int wsum[16];
  __shared__ int carry_s;
  const int t = threadIdx.x;
  const int wv = t >> 6, ln = t & 63;
  if (t == 0) carry_s = 0;
  __syncthreads();
  for (int base = 0; base < n; base += 1024) {
    const int i = base + t;
    const int v = (i < n) ? cursor[i] : 0;
    // wave-wide inclusive scan (no barriers)
    int x = v;
#pragma unroll
    for (int off = 1; off < 64; off <<= 1) {
      int y = __shfl_up(x, off, 64);
      if (ln >= off) x += y;
    }
    if (ln == 63) wsum[wv] = x;
    __syncthreads();                       // B1: wave sums visible
    if (t < 16) {                          // lanes 0..15 of wave 0
      int s = wsum[t];
#pragma unroll
      for (int off = 1; off < 16; off <<= 1) {
        int y = __shfl_up(s, off, 64);
        if (t >= off) s += y;
      }
      wsum[t] = s;                         // inclusive scan of wave sums
    }
    __syncthreads();                       // B2: scanned sums visible
    const int prev  = (wv > 0) ? wsum[wv - 1] : 0;
    const int inc   = x + prev;            // chunk-inclusive scan
    const int carry = carry_s;
    if (i < n) {
      rowptr[i + 1] = carry + inc;
      cursor[i]     = carry + inc - v;     // exclusive (fill start offsets)
    }
    __syncthreads();                       // B3: all reads of carry_s/wsum done
    if (t == 1023) carry_s = carry + inc;  // chunk total
  }
  if (t == 0) rowptr[0] = 0;
}

// scatter reordered (src, w) directly -> kills the eid indirection in gathers
__global__ __launch_bounds__(256) void fill_csr(
    const int* __restrict__ dst, const int* __restrict__ src,
    const float* __restrict__ w, int* __restrict__ cursor,
    int* __restrict__ es, float* __restrict__ ws, int E) {
  int e = blockIdx.x * blockDim.x + threadIdx.x;
  if (e < E) {
    int pos = atomicAdd(&cursor[dst[e]], 1);
    es[pos] = src[e];
    ws[pos] = w[e];
  }
}

// ------- gather layer1: bf16 S [Nn,512] -> bf16 out (bias+relu fused) -------
// 64 thr/node; edge metadata loaded once per 64-edge batch (coalesced),
// broadcast via shfl -> row load is the only memory op in the inner loop.
__global__ __launch_bounds__(256) void gather1_b2b(
    const unsigned short* __restrict__ S, const int* __restrict__ es,
    const float* __restrict__ ws, const int* __restrict__ rowptr,
    const float* __restrict__ bias, unsigned short* __restrict__ out, int Nn) {
  const int tn = threadIdx.x & 63;                 // 64 thr/node, 8 bf16 each
  const int node = blockIdx.x * 4 + (threadIdx.x >> 6);
  if (node >= Nn) return;
  const int f = tn << 3;
  float acc[8] = {};
  const int beg = rowptr[node], end = rowptr[node + 1];
  for (int b = beg; b < end; b += 64) {
    const int m = end - b;
    int   sv_l = 0;
    float w_l  = 0.f;
    if (tn < m) { sv_l = es[b + tn]; w_l = ws[b + tn]; }
    const int cnt = (m < 64) ? m : 64;
    for (int i = 0; i < cnt; ++i) {
      const int   sv = __shfl(sv_l, i, 64);
      const float ww = __shfl(w_l, i, 64);
      const uint4 u = *(const uint4*)(S + (size_t)sv * 512 + f);
      acc[0] = fmaf(bflo(u.x), ww, acc[0]);
      acc[1] = fmaf(bfhi(u.x), ww, acc[1]);
      acc[2] = fmaf(bflo(u.y), ww, acc[2]);
      acc[3] = fmaf(bfhi(u.y), ww, acc[3]);
      acc[4] = fmaf(bflo(u.z), ww, acc[4]);
      acc[5] = fmaf(bfhi(u.z), ww, acc[5]);
      acc[6] = fmaf(bflo(u.w), ww, acc[6]);
      acc[7] = fmaf(bfhi(u.w), ww, acc[7]);
    }
  }
  float r[8];
#pragma unroll
  for (int j = 0; j < 8; ++j) r[j] = fmaxf(acc[j] + bias[f + j], 0.f);
  uint4 o;
  o.x = (unsigned int)rnbf(r[0]) | ((unsigned int)rnbf(r[1]) << 16);
  o.y = (unsigned int)rnbf(r[2]) | ((unsigned int)rnbf(r[3]) << 16);
  o.z = (unsigned int)rnbf(r[4]) | ((unsigned int)rnbf(r[5]) << 16);
  o.w = (unsigned int)rnbf(r[6]) | ((unsigned int)rnbf(r[7]) << 16);
  *(uint4*)(out + (size_t)node * 512 + f) = o;
}

// ------- gather layer2: bf16 S [Nn,256] -> f32 out (bias+relu fused) --------
__global__ __launch_bounds__(256) void gather2_b2f(
    const unsigned short* __restrict__ S, const int* __restrict__ es,
    const float* __restrict__ ws, const int* __restrict__ rowptr,
    const float* __restrict__ bias, float* __restrict__ out, int Nn) {
  const int tn = threadIdx.x & 31;                 // 32 thr/node, 8 bf16 each
  const int node = blockIdx.x * 8 + (threadIdx.x >> 5);
  if (node >= Nn) return;
  const int f = tn << 3;
  float acc[8] = {};
  const int beg = rowptr[node], end = rowptr[node + 1];
  for (int b = beg; b < end; b += 32) {
    const int m = end - b;
    int   sv_l = 0;
    float w_l  = 0.f;
    if (tn < m) { sv_l = es[b + tn]; w_l = ws[b + tn]; }
    const int cnt = (m < 32) ? m : 32;
    for (int i = 0; i < cnt; ++i) {
      const int   sv = __shfl(sv_l, i, 32);
      const float ww = __shfl(w_l, i, 32);
      const uint4 u = *(const uint4*)(S + (size_t)sv * 256 + f);
      acc[0] = fmaf(bflo(u.x), ww, acc[0]);
      acc[1] = fmaf(bfhi(u.x), ww, acc[1]);
      acc[2] = fmaf(bflo(u.y), ww, acc[2]);
      acc[3] = fmaf(bfhi(u.y), ww, acc[3]);
      acc[4] = fmaf(bflo(u.z), ww, acc[4]);
      acc[5] = fmaf(bfhi(u.z), ww, acc[5]);
      acc[6] = fmaf(bflo(u.w), ww, acc[6]);
      acc[7] = fmaf(bfhi(u.w), ww, acc[7]);
    }
  }
  float4 o1, o2;
  o1.x = fmaxf(acc[0] + bias[f + 0], 0.f);
  o1.y = fmaxf(acc[1] + bias[f + 1], 0.f);
  o1.z = fmaxf(acc[2] + bias[f + 2], 0.f);
  o1.w = fmaxf(acc[3] + bias[f + 3], 0.f);
  o2.x = fmaxf(acc[4] + bias[f + 4], 0.f);
  o2.y = fmaxf(acc[5] + bias[f + 5], 0.f);
  o2.z = fmaxf(acc[6] + bias[f + 6], 0.f);
  o2.w = fmaxf(acc[7] + bias[f + 7], 0.f);
  *(float4*)(out + (size_t)node * 256 + f) = o1;
  *(float4*)(out + (size_t)node * 256 + f + 4) = o2;
}

// ============================================================================
extern "C" void kernel_launch(void* const* d_in, const int* in_sizes, int n_in,
                              void* d_out, int out_size, void* d_ws, size_t ws_size,
                              hipStream_t stream) {
  const float* x  = (const float*)d_in[0];
  const int*   ei = (const int*)d_in[1];
  const float* ew = (const float*)d_in[2];
  const float* W1 = (const float*)d_in[3];
  const float* b1 = (const float*)d_in[4];
  const float* W2 = (const float*)d_in[5];
  const float* b2 = (const float*)d_in[6];

  const int D_IN = 1024, D_HID = 512, D_LAT = 256;
  const int Nn = in_sizes[0] / D_IN;   // 50000
  const int E  = in_sizes[2];          // 400000
  const int* src  = ei;
  const int* dstp = ei + E;

  // ws layout (region A aliases xb->hb, region B aliases s1->s2):
  //  A: [0, Nn*1024*2)            xb bf16; later hb bf16 (Nn*512*2 <= that)
  //  B: [A, A + Nn*512*2)         s1 bf16; later s2 bf16 (Nn*256*2 <= that)
  //  C: W1t, W2t, rowptr, cursor, es, ws                  (~5 MB)
  char* base = (char*)d_ws;
  const size_t szA = (size_t)Nn * D_IN * 2;
  const size_t szB = (size_t)Nn * D_HID * 2;
  unsigned short* xb  = (unsigned short*)base;
  unsigned short* hb  = (unsigned short*)base;             // alias, xb dead
  unsigned short* s1  = (unsigned short*)(base + szA);
  unsigned short* s2  = (unsigned short*)(base + szA);     // alias, s1 dead
  char* tail = base + szA + szB;
  unsigned short* W1t = (unsigned short*)tail;
  unsigned short* W2t = W1t + (size_t)D_IN * D_HID;
  int*   rowptr = (int*)(W2t + (size_t)D_HID * D_LAT);
  int*   cursor = rowptr + (Nn + 1);
  int*   es     = cursor + Nn;
  float* wsrt   = (float*)(es + E);

  // ---- CSR build ----
  hipMemsetAsync(cursor, 0, (size_t)Nn * sizeof(int), stream);
  hist_dst<<<(E + 255) / 256, 256, 0, stream>>>(dstp, cursor, E);
  scan_csr<<<1, 1024, 0, stream>>>(cursor, rowptr, Nn);
  fill_csr<<<(E + 255) / 256, 256, 0, stream>>>(dstp, src, ew, cursor, es, wsrt, E);

  // ---- casts ----
  long long n4 = (long long)Nn * D_IN / 4;
  cast_f32_to_bf16<<<(int)((n4 + 255) / 256), 256, 0, stream>>>(x, xb, n4);
  transpose_cast_bf16<<<dim3(D_HID / 32, D_IN / 32), 256, 0, stream>>>(
      W1, W1t, D_IN, D_HID);
  transpose_cast_bf16<<<dim3(D_LAT / 32, D_HID / 32), 256, 0, stream>>>(
      W2, W2t, D_HID, D_LAT);

  // ---- layer 1 ----
  dim3 g1(D_HID / TN, (Nn + TM - 1) / TM);
  gemm_bf16<<<g1, 256, 0, stream>>>(xb, W1t, s1, Nn, D_HID, D_IN);
  gather1_b2b<<<(Nn + 3) / 4, 256, 0, stream>>>(
      s1, es, wsrt, rowptr, b1, hb, Nn);

  // ---- layer 2 ----
  dim3 g2(D_LAT / TN, (Nn + TM - 1) / TM);
  gemm_bf16<<<g2, 256, 0, stream>>>(hb, W2t, s2, Nn, D_LAT, D_HID);
  gather2_b2f<<<(Nn + 7) / 8, 256, 0, stream>>>(
      s2, es, wsrt, rowptr, b2, (float*)d_out, Nn);
}